// Round 6
// baseline (399.274 us; speedup 1.0000x reference)
//
#include <hip/hip_runtime.h>
#include <hip/hip_fp16.h>

typedef _Float16 half8 __attribute__((ext_vector_type(8)));
typedef float floatx4 __attribute__((ext_vector_type(4)));

// ---------------- prepack: conv Bfrags + FC weights in MFMA B-frag layout ---
__global__ void k_prepack(const float* __restrict__ WhW, const float* __restrict__ Whb,
                          const float* __restrict__ WinW, const float* __restrict__ PcW,
                          const int* __restrict__ dom,
                          const float* __restrict__ PlW, const float* __restrict__ WfcW,
                          __half* __restrict__ Bpack, float* __restrict__ bias48,
                          __half* __restrict__ B48,
                          __half* __restrict__ BfcP, __half* __restrict__ BfcH) {
  const int gid = blockIdx.x * 256 + threadIdx.x;
  const int gstride = gridDim.x * 256;
  const int dm = dom[0];
  // Bp: hid conv2/conv3 B fragments (unchanged layout)
  for (int i = gid; i < 11 * 3 * 64 * 8; i += gstride) {
    const int j = i & 7, lane = (i >> 3) & 63, nt = (i >> 9) % 3, s = i / 1536;
    const int n = lane & 15, q = lane >> 4;
    const int k = q * 8 + j;
    const int oc = nt * 16 + n;
    int tap, ch; bool valid = true;
    if (s < 9)       { tap = s;      ch = k; }
    else if (s == 9) { tap = k >> 2; ch = 32 + (k & 3); }
    else             { tap = 8;      ch = 32 + k; valid = (k < 4); }
    float v = 0.f;
    if (valid && oc < 36 && ch < 36) v = WhW[(oc * 36 + ch) * 9 + tap];
    Bpack[i] = __float2half(v);
  }
  if (gid < 48) bias48[gid] = (gid < 36) ? Whb[gid] : 0.f;
  // B48: unified conv1 fragments [3 m][3 nt][64 lanes][8 j].
  // k = m*32 + q*8 + j; tap = m*4+q (taps 0..8 row-major of 3x3); slot = j.
  // slots 0..2 = x_s channels (shared conv, oc<36); slots 4..6 = x_p channels
  // (priv conv, oc in 36..47 -> pc = oc-36); slots 3,7 zero.
  for (int i = gid; i < 4608; i += gstride) {
    const int j = i & 7, lane = (i >> 3) & 63, nt = (i >> 9) % 3, s = i / 1536;
    const int n = lane & 15, q = lane >> 4, oc = nt * 16 + n;
    const int tap = s * 4 + q;
    float v = 0.f;
    if (tap <= 8) {
      const int ky = tap / 3, kx = tap % 3;
      if (j < 3 && oc < 36) v = WinW[((oc * 3 + j) * 3 + ky) * 3 + kx];
      else if (j >= 4 && j < 7 && oc >= 36)
        v = PcW[(size_t)dm * 324 + ((oc - 36) * 3 + (j - 4)) * 9 + ky * 3 + kx];
    }
    B48[i] = __float2half(v);
  }
  // BfcP: [384 ksteps][64 lanes][8]  B-frag for P-FC (K order = pix*12+oc)
  for (int i = gid; i < 196608; i += gstride) {
    const int j = i & 7, lane = (i >> 3) & 63, step = i >> 9;
    const int hid = lane & 15, q = lane >> 4;
    const int k = step * 32 + q * 8 + j;
    float v = 0.f;
    if (hid < 12) v = PlW[((size_t)dm * 12 + hid) * 12288 + (k % 12) * 1024 + (k / 12)];
    BfcP[i] = __float2half(v);
  }
  // BfcH: [72 ksteps][64 lanes][8]  B-frag for shared-FC (K order = px_lin*36+oc)
  for (int i = gid; i < 36864; i += gstride) {
    const int j = i & 7, lane = (i >> 3) & 63, step = i >> 9;
    const int hid = lane & 15, q = lane >> 4;
    const int k = step * 32 + q * 8 + j;
    float v = 0.f;
    if (hid < 12) v = WfcW[hid * 2304 + (k % 36) * 64 + (k / 36)];
    BfcH[i] = __float2half(v);
  }
}

// ---------------- persistent merged tower: unified conv + conv2 + conv3 -----
// 256 blocks x 4 images. LDS plan (162,176 B):
//   X   [0, 69,696):  img [66][66][8 halves] (both images interleaved);
//                     after the unified conv: Bpack [0,33,792) + O2h @33,792
//   A1h [69,696, 162,176): conv1-out records [34][34][40h] / fcstage
__global__ __launch_bounds__(1024, 4)
void k_tower(const float* __restrict__ xin_s, const float* __restrict__ xin_p,
             const __half* __restrict__ B48g, const float* __restrict__ Winb,
             const __half* __restrict__ Bpg, const float* __restrict__ b48g,
             const float* __restrict__ Pcb, const int* __restrict__ dom,
             __half* __restrict__ ptg_g, __half* __restrict__ hsg_g) {
  extern __shared__ __align__(16) char ldsx[];
  __half* X   = (__half*)ldsx;
  __half* O2h = X + 16896;                   // halves: byte 33,792
  __half* A1h = (__half*)(ldsx + 69696);
  const int tid = threadIdx.x;
  const int lane = tid & 63, wave = tid >> 6, ln = lane & 15, q = lane >> 4;
  const int dm = dom[0];

  // per-lane constants
  float bv36[2];
#pragma unroll
  for (int nt = 0; nt < 2; ++nt) bv36[nt] = Winb[nt * 16 + ln];
  const float wv2 = Winb[(ln < 4) ? (32 + ln) : 35];
  const float pv2 = Pcb[dm * 12 + ((ln >= 4) ? (ln - 4) : 0)];
  const float bv2 = (ln < 4) ? wv2 : pv2;
  float bb[3];
#pragma unroll
  for (int nt = 0; nt < 3; ++nt) bb[nt] = b48g[nt * 16 + ln];
  // unified-conv B fragments (loop-invariant)
  half8 Bu[3][3];
#pragma unroll
  for (int m = 0; m < 3; ++m)
#pragma unroll
    for (int nt = 0; nt < 3; ++nt)
      Bu[m][nt] = *(const half8*)(B48g + ((m * 3 + nt) * 64 + lane) * 8);
  // A-gather record offsets (halves) for MFMA m=0,1; m=2 handled separately
  int offA[2];
#pragma unroll
  for (int m = 0; m < 2; ++m) {
    const int tap = m * 4 + q;
    offA[m] = ((tap / 3) * 66 + (tap % 3) - 67) * 8;
  }
  const int zrec = (65 * 66 + 65) * 8;       // guaranteed-zero halo record

  const int sy = (tid << 2) >> 6, sx = (tid << 2) & 63;  // 4 pixels per thread
  // prefetch image 0
  float4 ps0, ps1, ps2, pp0, pp1, pp2;
  {
    const size_t o = (size_t)(blockIdx.x * 4) * 12288 + sy * 64 + sx;
    ps0 = *(const float4*)(xin_s + o);
    ps1 = *(const float4*)(xin_s + o + 4096);
    ps2 = *(const float4*)(xin_s + o + 8192);
    pp0 = *(const float4*)(xin_p + o);
    pp1 = *(const float4*)(xin_p + o + 4096);
    pp2 = *(const float4*)(xin_p + o + 8192);
  }

#pragma unroll 1
  for (int it = 0; it < 4; ++it) {
    const int b = blockIdx.x * 4 + it;

    // ---- P0: zero img + A1h halos; stage both images ----
    for (int i = tid; i < 260; i += 1024) {
      int r, c;
      if (i < 66)       { r = 0;  c = i; }
      else if (i < 132) { r = 65; c = i - 66; }
      else if (i < 196) { r = i - 132 + 1; c = 0; }
      else              { r = i - 196 + 1; c = 65; }
      *(uint4*)&X[(r * 66 + c) * 8] = make_uint4(0, 0, 0, 0);
    }
    for (int u = tid; u < 660; u += 1024) {
      const int rec = u / 5, part = u % 5;
      int r, c;
      if (rec < 34)       { r = 0;  c = rec; }
      else if (rec < 68)  { r = 33; c = rec - 34; }
      else if (rec < 100) { r = rec - 68 + 1;  c = 0; }
      else                { r = rec - 100 + 1; c = 33; }
      *(uint4*)&A1h[(r * 34 + c) * 40 + part * 8] = make_uint4(0, 0, 0, 0);
    }
    {
      const float* f0 = (const float*)&ps0;
      const float* f1 = (const float*)&ps1;
      const float* f2 = (const float*)&ps2;
      const float* g0 = (const float*)&pp0;
      const float* g1 = (const float*)&pp1;
      const float* g2 = (const float*)&pp2;
#pragma unroll
      for (int k2 = 0; k2 < 4; ++k2) {
        __half2 a = __floats2half2_rn(f0[k2], f1[k2]);
        __half2 bq = __floats2half2_rn(f2[k2], 0.f);
        __half2 c = __floats2half2_rn(g0[k2], g1[k2]);
        __half2 d = __floats2half2_rn(g2[k2], 0.f);
        *(uint4*)&X[((sy + 1) * 66 + sx + 1 + k2) * 8] =
            make_uint4(*(unsigned int*)&a, *(unsigned int*)&bq,
                       *(unsigned int*)&c, *(unsigned int*)&d);
      }
    }
    __syncthreads();

    // ---- U1: unified conv (48 oc) + 2x2 pool ----
    {
      __half* ptg = ptg_g + (size_t)b * 12288;
#pragma unroll 1
      for (int kk = 0; kk < 2; ++kk) {
        const int pr = 16 * kk + wave;
#pragma unroll
        for (int t = 0; t < 4; ++t) {
          floatx4 acc[2][3];
#pragma unroll
          for (int rb = 0; rb < 2; ++rb)
#pragma unroll
            for (int nt = 0; nt < 3; ++nt) acc[rb][nt] = (floatx4){0.f, 0.f, 0.f, 0.f};
#pragma unroll
          for (int rb = 0; rb < 2; ++rb) {
            const int yl = 2 * pr + rb + 1;
            const int xc = t * 16 + ln + 1;
            const int base = (yl * 66 + xc) * 8;
            const half8 A0 = *(const half8*)&X[base + offA[0]];
            const half8 A1 = *(const half8*)&X[base + offA[1]];
            const half8 A2 = *(const half8*)&X[(q == 0) ? (base + 67 * 8) : zrec];
#pragma unroll
            for (int nt = 0; nt < 3; ++nt) {
              acc[rb][nt] = __builtin_amdgcn_mfma_f32_16x16x32_f16(A0, Bu[0][nt], acc[rb][nt], 0, 0, 0);
              acc[rb][nt] = __builtin_amdgcn_mfma_f32_16x16x32_f16(A1, Bu[1][nt], acc[rb][nt], 0, 0, 0);
              acc[rb][nt] = __builtin_amdgcn_mfma_f32_16x16x32_f16(A2, Bu[2][nt], acc[rb][nt], 0, 0, 0);
            }
          }
          const int px = t * 8 + q * 2;
#pragma unroll
          for (int nt = 0; nt < 2; ++nt) {
            const int oc = nt * 16 + ln;
            const floatx4 ca = acc[0][nt], cb = acc[1][nt];
            const float v0 = fmaxf(fmaxf(fmaxf(ca.x, ca.y), fmaxf(cb.x, cb.y)) + bv36[nt], 0.f);
            const float v1 = fmaxf(fmaxf(fmaxf(ca.z, ca.w), fmaxf(cb.z, cb.w)) + bv36[nt], 0.f);
            A1h[((pr + 1) * 34 + px + 1) * 40 + oc] = __float2half(v0);
            A1h[((pr + 1) * 34 + px + 2) * 40 + oc] = __float2half(v1);
          }
          {
            const floatx4 ca = acc[0][2], cb = acc[1][2];
            float v0 = fmaxf(fmaxf(ca.x, ca.y), fmaxf(cb.x, cb.y)) + bv2;
            float v1 = fmaxf(fmaxf(ca.z, ca.w), fmaxf(cb.z, cb.w)) + bv2;
            if (ln < 4) {
              v0 = fmaxf(v0, 0.f); v1 = fmaxf(v1, 0.f);
              A1h[((pr + 1) * 34 + px + 1) * 40 + 32 + ln] = __float2half(v0);
              A1h[((pr + 1) * 34 + px + 2) * 40 + 32 + ln] = __float2half(v1);
            } else {
              v0 = (v0 > 0.f) ? v0 : 0.001f * v0;
              v1 = (v1 > 0.f) ? v1 : 0.001f * v1;
              const int pix = pr * 32 + px;
              ptg[pix * 12 + (ln - 4)]       = __float2half(v0);
              ptg[(pix + 1) * 12 + (ln - 4)] = __float2half(v1);
            }
          }
        }
      }
    }
    __syncthreads();

    // ---- T3: stage hid Bpack into X[0..); zero O2h halos ----
#pragma unroll
    for (int u = 0; u < 3; ++u) {
      const int i = tid + u * 1024;
      if (i < 2112) ((uint4*)X)[i] = ((const uint4*)Bpg)[i];
    }
    for (int u = tid; u < 340; u += 1024) {
      const int rec = u / 5, part = u % 5;
      int r, c;
      if (rec < 18)      { r = 0;  c = rec; }
      else if (rec < 36) { r = 17; c = rec - 18; }
      else if (rec < 52) { r = rec - 36 + 1; c = 0; }
      else               { r = rec - 52 + 1; c = 17; }
      *(uint4*)&O2h[(r * 18 + c) * 40 + part * 8] = make_uint4(0, 0, 0, 0);
    }
    __syncthreads();

    const __half* lB = X + lane * 8;
    const int tA = 2 * q, tB = 2 * q + 1;

    // ---- T4: conv2 + pool -> O2 records (16 waves x 1 pooled row) ----
    {
      const int roA = ((tA / 3) * 34 + (tA % 3)) * 40 + 32;
      const int roB = ((tB / 3) * 34 + (tB % 3)) * 40 + 32;
      const int roC = (2 * 34 + 2) * 40 + 32;
      const int r0 = 2 * wave;
      int baseA[4];
#pragma unroll
      for (int mt = 0; mt < 4; ++mt)
        baseA[mt] = ((r0 + (mt >> 1)) * 34 + (mt & 1) * 16 + ln) * 40 + q * 8;
      floatx4 acc[4][3];
#pragma unroll
      for (int mt = 0; mt < 4; ++mt)
#pragma unroll
        for (int nt = 0; nt < 3; ++nt) acc[mt][nt] = (floatx4){0.f, 0.f, 0.f, 0.f};
#pragma unroll
      for (int s = 0; s < 9; ++s) {
        const int ky = s / 3, kx = s % 3;
        const half8 B0 = *(const half8*)&lB[(s * 3 + 0) * 512];
        const half8 B1 = *(const half8*)&lB[(s * 3 + 1) * 512];
        const half8 B2 = *(const half8*)&lB[(s * 3 + 2) * 512];
#pragma unroll
        for (int mt = 0; mt < 4; ++mt) {
          const half8 A = *(const half8*)&A1h[baseA[mt] + (ky * 34 + kx) * 40];
          acc[mt][0] = __builtin_amdgcn_mfma_f32_16x16x32_f16(A, B0, acc[mt][0], 0, 0, 0);
          acc[mt][1] = __builtin_amdgcn_mfma_f32_16x16x32_f16(A, B1, acc[mt][1], 0, 0, 0);
          acc[mt][2] = __builtin_amdgcn_mfma_f32_16x16x32_f16(A, B2, acc[mt][2], 0, 0, 0);
        }
      }
#pragma unroll
      for (int s = 9; s <= 10; ++s) {
        const half8 B0 = *(const half8*)&lB[(s * 3 + 0) * 512];
        const half8 B1 = *(const half8*)&lB[(s * 3 + 1) * 512];
        const half8 B2 = *(const half8*)&lB[(s * 3 + 2) * 512];
        const int oA = (s == 9) ? roA : roC, oB = (s == 9) ? roB : roC;
#pragma unroll
        for (int mt = 0; mt < 4; ++mt) {
          union { half8 h; uint2 u[2]; } au;
          au.u[0] = *(const uint2*)&A1h[baseA[mt] + oA];
          au.u[1] = *(const uint2*)&A1h[baseA[mt] + oB];
          acc[mt][0] = __builtin_amdgcn_mfma_f32_16x16x32_f16(au.h, B0, acc[mt][0], 0, 0, 0);
          acc[mt][1] = __builtin_amdgcn_mfma_f32_16x16x32_f16(au.h, B1, acc[mt][1], 0, 0, 0);
          acc[mt][2] = __builtin_amdgcn_mfma_f32_16x16x32_f16(au.h, B2, acc[mt][2], 0, 0, 0);
        }
      }
      const int py = wave;
#pragma unroll
      for (int h = 0; h < 2; ++h)
#pragma unroll
        for (int nt = 0; nt < 3; ++nt) {
          const int oc = nt * 16 + ln;
          if (oc < 36) {
            const floatx4 ca = acc[h][nt], cb = acc[2 + h][nt];
            const float v0 = fmaxf(fmaxf(fmaxf(ca.x, ca.y), fmaxf(cb.x, cb.y)) + bb[nt], 0.f);
            const float v1 = fmaxf(fmaxf(fmaxf(ca.z, ca.w), fmaxf(cb.z, cb.w)) + bb[nt], 0.f);
            const int px = h * 8 + q * 2;
            O2h[((py + 1) * 18 + px + 1) * 40 + oc] = __float2half(v0);
            O2h[((py + 1) * 18 + px + 2) * 40 + oc] = __float2half(v1);
          }
        }
    }
    __syncthreads();

    // prefetch next image (loads span T5/T6)
    if (it < 3) {
      const size_t o = (size_t)(b + 1) * 12288 + sy * 64 + sx;
      ps0 = *(const float4*)(xin_s + o);
      ps1 = *(const float4*)(xin_s + o + 4096);
      ps2 = *(const float4*)(xin_s + o + 8192);
      pp0 = *(const float4*)(xin_p + o);
      pp1 = *(const float4*)(xin_p + o + 4096);
      pp2 = *(const float4*)(xin_p + o + 8192);
    }

    // ---- T5: conv3 + pool -> fcstage (first 8 waves) ----
    if (wave < 8) {
      const int roA = ((tA / 3) * 18 + (tA % 3)) * 40 + 32;
      const int roB = ((tB / 3) * 18 + (tB % 3)) * 40 + 32;
      const int roC = (2 * 18 + 2) * 40 + 32;
      int baseA[2];
#pragma unroll
      for (int mt = 0; mt < 2; ++mt)
        baseA[mt] = ((2 * wave + mt) * 18 + ln) * 40 + q * 8;
      floatx4 acc[2][3];
#pragma unroll
      for (int mt = 0; mt < 2; ++mt)
#pragma unroll
        for (int nt = 0; nt < 3; ++nt) acc[mt][nt] = (floatx4){0.f, 0.f, 0.f, 0.f};
#pragma unroll
      for (int s = 0; s < 9; ++s) {
        const int ky = s / 3, kx = s % 3;
        const half8 B0 = *(const half8*)&lB[(s * 3 + 0) * 512];
        const half8 B1 = *(const half8*)&lB[(s * 3 + 1) * 512];
        const half8 B2 = *(const half8*)&lB[(s * 3 + 2) * 512];
#pragma unroll
        for (int mt = 0; mt < 2; ++mt) {
          const half8 A = *(const half8*)&O2h[baseA[mt] + (ky * 18 + kx) * 40];
          acc[mt][0] = __builtin_amdgcn_mfma_f32_16x16x32_f16(A, B0, acc[mt][0], 0, 0, 0);
          acc[mt][1] = __builtin_amdgcn_mfma_f32_16x16x32_f16(A, B1, acc[mt][1], 0, 0, 0);
          acc[mt][2] = __builtin_amdgcn_mfma_f32_16x16x32_f16(A, B2, acc[mt][2], 0, 0, 0);
        }
      }
#pragma unroll
      for (int s = 9; s <= 10; ++s) {
        const half8 B0 = *(const half8*)&lB[(s * 3 + 0) * 512];
        const half8 B1 = *(const half8*)&lB[(s * 3 + 1) * 512];
        const half8 B2 = *(const half8*)&lB[(s * 3 + 2) * 512];
        const int oA = (s == 9) ? roA : roC, oB = (s == 9) ? roB : roC;
#pragma unroll
        for (int mt = 0; mt < 2; ++mt) {
          union { half8 h; uint2 u[2]; } au;
          au.u[0] = *(const uint2*)&O2h[baseA[mt] + oA];
          au.u[1] = *(const uint2*)&O2h[baseA[mt] + oB];
          acc[mt][0] = __builtin_amdgcn_mfma_f32_16x16x32_f16(au.h, B0, acc[mt][0], 0, 0, 0);
          acc[mt][1] = __builtin_amdgcn_mfma_f32_16x16x32_f16(au.h, B1, acc[mt][1], 0, 0, 0);
          acc[mt][2] = __builtin_amdgcn_mfma_f32_16x16x32_f16(au.h, B2, acc[mt][2], 0, 0, 0);
        }
      }
#pragma unroll
      for (int nt = 0; nt < 3; ++nt) {
        const int oc = nt * 16 + ln;
        if (oc < 36) {
          const floatx4 ca = acc[0][nt], cb = acc[1][nt];
          const float v0 = fmaxf(fmaxf(fmaxf(ca.x, ca.y), fmaxf(cb.x, cb.y)) + bb[nt], 0.f);
          const float v1 = fmaxf(fmaxf(fmaxf(ca.z, ca.w), fmaxf(cb.z, cb.w)) + bb[nt], 0.f);
          const int px = q * 2;
          A1h[(wave * 8 + px) * 36 + oc]     = __float2half(v0);
          A1h[(wave * 8 + px + 1) * 36 + oc] = __float2half(v1);
        }
      }
    }
    __syncthreads();

    // ---- T6: flush fcstage to global ----
    if (tid < 288)
      ((uint4*)(hsg_g + (size_t)b * 2304))[tid] = ((const uint4*)A1h)[tid];
    __syncthreads();   // protect A1h/X from next iteration's P0
  }
}

// ---------------- batched FC GEMMs + fused MoE heads -------------------------
// 256 blocks x 8 waves; 4 images/block; hb/pb never leave LDS.
__global__ __launch_bounds__(512)
void k_tail(const __half* __restrict__ ptg, const __half* __restrict__ hsg,
            const __half* __restrict__ BfcP, const __half* __restrict__ BfcH,
            const float* __restrict__ Plb, const float* __restrict__ Wfcb,
            const int* __restrict__ dom, const int* __restrict__ tt,
            const float* __restrict__ W1, const float* __restrict__ b1,
            const float* __restrict__ W2, const float* __restrict__ b2,
            const float* __restrict__ W3, const float* __restrict__ b3,
            float* __restrict__ out) {
  __shared__ float red[8][16][16];
  __shared__ float xls[4][24];   // [img][ h(0..11) | p(12..23) ]
  __shared__ float h1l[4][28];
  __shared__ float h2l[4][14];
  const int tid = threadIdx.x, wave = tid >> 6, lane = tid & 63;
  const int ln = lane & 15, q = lane >> 4;
  const int m0 = blockIdx.x * 4, dm = dom[0];
  const int mr = m0 + (ln & 3);

  floatx4 accP = (floatx4){0.f, 0.f, 0.f, 0.f};
  const __half* arow = ptg + (size_t)mr * 12288 + q * 8;
#pragma unroll 4
  for (int s = wave; s < 384; s += 8) {
    const half8 A = *(const half8*)(arow + s * 32);
    const half8 B = *(const half8*)(BfcP + (size_t)(s * 64 + lane) * 8);
    accP = __builtin_amdgcn_mfma_f32_16x16x32_f16(A, B, accP, 0, 0, 0);
  }
  floatx4 accH = (floatx4){0.f, 0.f, 0.f, 0.f};
  const __half* hrow = hsg + (size_t)mr * 2304 + q * 8;
#pragma unroll
  for (int s = wave; s < 72; s += 8) {
    const half8 A = *(const half8*)(hrow + s * 32);
    const half8 B = *(const half8*)(BfcH + (size_t)(s * 64 + lane) * 8);
    accH = __builtin_amdgcn_mfma_f32_16x16x32_f16(A, B, accH, 0, 0, 0);
  }
#pragma unroll
  for (int r = 0; r < 4; ++r) red[wave][4 * q + r][ln] = accP[r];
  __syncthreads();
  if (tid < 256) {
    const int m = tid >> 4, n = tid & 15;
    float s = 0.f;
#pragma unroll
    for (int w = 0; w < 8; ++w) s += red[w][m][n];
    if (m < 4 && n < 12) xls[m][12 + n] = s + Plb[dm * 12 + n];
  }
  __syncthreads();
#pragma unroll
  for (int r = 0; r < 4; ++r) red[wave][4 * q + r][ln] = accH[r];
  __syncthreads();
  if (tid < 256) {
    const int m = tid >> 4, n = tid & 15;
    float s = 0.f;
#pragma unroll
    for (int w = 0; w < 8; ++w) s += red[w][m][n];
    if (m < 4 && n < 12) xls[m][n] = fmaxf(s + Wfcb[n], 0.f);
  }
  __syncthreads();
  // heads: H1 (4x28), H2 (4x14), H3 (4x5)
  if (tid < 112) {
    const int img = tid / 28, row = tid % 28;
    const int t = tt[m0 + img];
    const float* w = W1 + t * 672 + row * 24;
    float s = b1[t * 28 + row];
#pragma unroll
    for (int j = 0; j < 24; ++j) s = fmaf(w[j], xls[img][j], s);
    h1l[img][row] = fmaxf(s, 0.f);
  }
  __syncthreads();
  if (tid < 56) {
    const int img = tid / 14, row = tid % 14;
    const int t = tt[m0 + img];
    const float* w = W2 + t * 392 + row * 28;
    float s = b2[t * 14 + row];
#pragma unroll
    for (int j = 0; j < 28; ++j) s = fmaf(w[j], h1l[img][j], s);
    h2l[img][row] = fmaxf(s, 0.f);
  }
  __syncthreads();
  if (tid < 20) {
    const int img = tid / 5, row = tid % 5;
    const int t = tt[m0 + img];
    const float* w = W3 + t * 70 + row * 14;
    float s = b3[t * 5 + row];
#pragma unroll
    for (int j = 0; j < 14; ++j) s = fmaf(w[j], h2l[img][j], s);
    out[(m0 + img) * 5 + row] = s;
  }
}

extern "C" void kernel_launch(void* const* d_in, const int* in_sizes, int n_in,
                              void* d_out, int out_size, void* d_ws, size_t ws_size,
                              hipStream_t stream) {
  const float* x_s  = (const float*)d_in[0];
  const float* x_p  = (const float*)d_in[1];
  const int*   tt   = (const int*)d_in[2];
  const int*   dom  = (const int*)d_in[3];
  const float* WinW = (const float*)d_in[4];
  const float* Winb = (const float*)d_in[5];
  const float* WhW  = (const float*)d_in[6];
  const float* Whb  = (const float*)d_in[7];
  const float* WfcW = (const float*)d_in[8];
  const float* Wfcb = (const float*)d_in[9];
  const float* PcW  = (const float*)d_in[10];
  const float* Pcb  = (const float*)d_in[11];
  const float* PlW  = (const float*)d_in[12];
  const float* Plb  = (const float*)d_in[13];
  const float* H1W  = (const float*)d_in[14];
  const float* H1b  = (const float*)d_in[15];
  const float* H2W  = (const float*)d_in[16];
  const float* H2b  = (const float*)d_in[17];
  const float* H3W  = (const float*)d_in[18];
  const float* H3b  = (const float*)d_in[19];
  float* out = (float*)d_out;

  char* ws = (char*)d_ws;
  __half* Bp   = (__half*)(ws + 0);          //    33,792 B
  float*  b48  = (float*)(ws + 33792);       //       192 B
  __half* B48  = (__half*)(ws + 33984);      //     9,216 B
  __half* BfcP = (__half*)(ws + 43200);      //   393,216 B
  __half* BfcH = (__half*)(ws + 436416);     //    73,728 B
  __half* hsg  = (__half*)(ws + 510144);     // 4,718,592 B  [1024][2304] f16
  __half* ptg  = (__half*)(ws + 5228736);    // 25,165,824 B [1024][12288] f16

  k_prepack<<<104, 256, 0, stream>>>(WhW, Whb, WinW, PcW, dom, PlW, WfcW,
                                     Bp, b48, B48, BfcP, BfcH);
  k_tower<<<256, 1024, 162176, stream>>>(x_s, x_p, B48, Winb, Bp, b48,
                                         Pcb, dom, ptg, hsg);
  k_tail<<<256, 512, 0, stream>>>(ptg, hsg, BfcP, BfcH, Plb, Wfcb, dom, tt,
                                  H1W, H1b, H2W, H2b, H3W, H3b, out);
}